// Round 1
// baseline (630.096 us; speedup 1.0000x reference)
//
#include <hip/hip_runtime.h>

typedef __bf16 bf16_t;
typedef __bf16 bf16x8 __attribute__((ext_vector_type(8)));
typedef __bf16 bf16x4 __attribute__((ext_vector_type(4)));
typedef float f32x4 __attribute__((ext_vector_type(4)));

constexpr int TDIM = 8192;
constexpr int KDIM = 4096;
constexpr int ODIM = 4096;
constexpr int BM = 128, BN = 128, BK = 32;

// Async global->LDS, 16B per lane. LDS dest must be wave-uniform base + lane*16.
__device__ __forceinline__ void async_ld16(void* lds, const void* g) {
    __builtin_amdgcn_global_load_lds(
        (const __attribute__((address_space(1))) unsigned int*)g,
        (__attribute__((address_space(3))) unsigned int*)lds,
        16, 0, 0);
}

// fp32 -> bf16 elementwise convert, 8 elems/thread, exact grid (n % 2048 == 0)
__global__ __launch_bounds__(256) void cvt_kernel(const float* __restrict__ src,
                                                  bf16_t* __restrict__ dst) {
    const size_t i = ((size_t)blockIdx.x * 256 + threadIdx.x) * 8;
    const float4 v0 = *(const float4*)(src + i);
    const float4 v1 = *(const float4*)(src + i + 4);
    bf16x8 o;
    o[0] = (bf16_t)v0.x; o[1] = (bf16_t)v0.y; o[2] = (bf16_t)v0.z; o[3] = (bf16_t)v0.w;
    o[4] = (bf16_t)v1.x; o[5] = (bf16_t)v1.y; o[6] = (bf16_t)v1.z; o[7] = (bf16_t)v1.w;
    *(bf16x8*)(dst + i) = o;
}

// C[t,o] = sum_k A[t,k]*B[o,k], both K-contiguous (NT gemm), fused dequant epilogue.
// m97 structure: 128x128 block tile, BK=32, 4 waves in 2x2, each wave 64x64 (4x4 MFMA tiles).
template <bool USE_DMA>
__global__ __launch_bounds__(256) void gemm_kernel(
    const bf16_t* __restrict__ A, const bf16_t* __restrict__ B,
    const float* __restrict__ Afp, const float* __restrict__ Bfp,
    const float* __restrict__ scale_x, const float* __restrict__ scale_w,
    const float* __restrict__ gscale, const float* __restrict__ bias,
    float* __restrict__ out) {
    __shared__ bf16_t sA[BM * BK];  // 8 KiB, row-major, NO padding (DMA layout constraint)
    __shared__ bf16_t sB[BN * BK];  // 8 KiB

    const int tid = threadIdx.x;
    const int bn = blockIdx.x & 31;   // 32 N-tiles
    const int bm = blockIdx.x >> 5;   // 64 M-tiles
    const int row0 = bm * BM;
    const int col0 = bn * BN;

    const int lane = tid & 63;
    const int wid = tid >> 6;
    const int wm = (wid >> 1) * 64;
    const int wn = (wid & 1) * 64;
    const int fr = lane & 15;        // row (A) / col (B) within 16
    const int fk = (lane >> 4) * 8;  // k offset: 0/8/16/24

    f32x4 acc[4][4] = {};

    // DMA staging addresses: thread t loads row t>>2, 16B chunk (t&3)*8 elems.
    // LDS offset = tid*16 B (contiguous lane-ordered => wave-uniform base + lane*16). 
    const size_t a_g = (size_t)(row0 + (tid >> 2)) * KDIM + (tid & 3) * 8;
    const size_t b_g = (size_t)(col0 + (tid >> 2)) * KDIM + (tid & 3) * 8;
    const int lds_off = tid * 8;  // elements

    for (int k0 = 0; k0 < KDIM; k0 += BK) {
        if (USE_DMA) {
            async_ld16(&sA[lds_off],        A + a_g + k0);
            async_ld16(&sA[2048 + lds_off], A + a_g + (size_t)64 * KDIM + k0);
            async_ld16(&sB[lds_off],        B + b_g + k0);
            async_ld16(&sB[2048 + lds_off], B + b_g + (size_t)64 * KDIM + k0);
        } else {
            // fallback: load fp32, convert in regs, ds_write
            const int r = tid >> 3;
            const int kc = (tid & 7) * 4;
#pragma unroll
            for (int h = 0; h < 4; ++h) {
                const float4 va = *(const float4*)(Afp + (size_t)(row0 + r + h * 32) * KDIM + k0 + kc);
                const float4 vb = *(const float4*)(Bfp + (size_t)(col0 + r + h * 32) * KDIM + k0 + kc);
                bf16x4 pa, pb;
                pa[0] = (bf16_t)va.x; pa[1] = (bf16_t)va.y; pa[2] = (bf16_t)va.z; pa[3] = (bf16_t)va.w;
                pb[0] = (bf16_t)vb.x; pb[1] = (bf16_t)vb.y; pb[2] = (bf16_t)vb.z; pb[3] = (bf16_t)vb.w;
                *(bf16x4*)&sA[(r + h * 32) * BK + kc] = pa;
                *(bf16x4*)&sB[(r + h * 32) * BK + kc] = pb;
            }
        }
        __syncthreads();  // drains vmcnt (global_load_lds) + lgkmcnt before compute

        bf16x8 af[4], bfr[4];
#pragma unroll
        for (int mt = 0; mt < 4; ++mt)
            af[mt] = *(const bf16x8*)&sA[(wm + mt * 16 + fr) * BK + fk];
#pragma unroll
        for (int nt = 0; nt < 4; ++nt)
            bfr[nt] = *(const bf16x8*)&sB[(wn + nt * 16 + fr) * BK + fk];
#pragma unroll
        for (int mt = 0; mt < 4; ++mt)
#pragma unroll
            for (int nt = 0; nt < 4; ++nt)
                acc[mt][nt] = __builtin_amdgcn_mfma_f32_16x16x32_bf16(af[mt], bfr[nt], acc[mt][nt], 0, 0, 0);
        __syncthreads();  // all waves done reading LDS before next stage overwrites
    }

    // Epilogue: C/D layout col=lane&15, row=(lane>>4)*4+reg [m89/m91-verified]
    const float gs = gscale[0];
    const int rbase = (lane >> 4) * 4;
#pragma unroll
    for (int nt = 0; nt < 4; ++nt) {
        const int o = col0 + wn + nt * 16 + fr;
        const float swv = scale_w[o] * gs;
        const float bv = bias[o];
#pragma unroll
        for (int mt = 0; mt < 4; ++mt) {
#pragma unroll
            for (int i = 0; i < 4; ++i) {
                const int t = row0 + wm + mt * 16 + rbase + i;
                out[(size_t)t * ODIM + o] = acc[mt][nt][i] * (scale_x[t] * swv) + bv;
            }
        }
    }
}

extern "C" void kernel_launch(void* const* d_in, const int* in_sizes, int n_in,
                              void* d_out, int out_size, void* d_ws, size_t ws_size,
                              hipStream_t stream) {
    const float* qx   = (const float*)d_in[0];  // (T,K) quantized acts (ints in fp32)
    const float* W    = (const float*)d_in[1];  // (O,K) quantized weights
    const float* sx   = (const float*)d_in[2];  // (T,1)
    const float* sw   = (const float*)d_in[3];  // (O,)
    const float* gs   = (const float*)d_in[4];  // (1,)
    const float* bias = (const float*)d_in[5];  // (O,)
    float* out = (float*)d_out;

    const size_t nA = (size_t)TDIM * KDIM;  // 33.5M
    const size_t nW = (size_t)ODIM * KDIM;  // 16.8M
    const dim3 grid(2048);  // 64 M-tiles x 32 N-tiles

    if (ws_size >= (nA + nW) * sizeof(bf16_t)) {
        bf16_t* Abf = (bf16_t*)d_ws;
        bf16_t* Wbf = Abf + nA;
        cvt_kernel<<<dim3(nA / 2048), dim3(256), 0, stream>>>(qx, Abf);
        cvt_kernel<<<dim3(nW / 2048), dim3(256), 0, stream>>>(W, Wbf);
        gemm_kernel<true><<<grid, dim3(256), 0, stream>>>(
            Abf, Wbf, nullptr, nullptr, sx, sw, gs, bias, out);
    } else {
        gemm_kernel<false><<<grid, dim3(256), 0, stream>>>(
            nullptr, nullptr, qx, W, sx, sw, gs, bias, out);
    }
}

// Round 2
// 568.747 us; speedup vs baseline: 1.1079x; 1.1079x over previous
//
#include <hip/hip_runtime.h>

typedef __bf16 bf16_t;
typedef __bf16 bf16x8 __attribute__((ext_vector_type(8)));
typedef __bf16 bf16x4 __attribute__((ext_vector_type(4)));
typedef float f32x4 __attribute__((ext_vector_type(4)));

constexpr int TDIM = 8192;
constexpr int KDIM = 4096;
constexpr int ODIM = 4096;
constexpr int BM = 128, BN = 128, BK = 32;

// Async global->LDS, 16B per lane. LDS dest is wave-uniform base + lane*16 (fixed);
// the per-lane global SOURCE address is free -> we put the bank swizzle there.
__device__ __forceinline__ void async_ld16(void* lds, const void* g) {
    __builtin_amdgcn_global_load_lds(
        (const __attribute__((address_space(1))) unsigned int*)g,
        (__attribute__((address_space(3))) unsigned int*)lds,
        16, 0, 0);
}

// fp32 -> bf16 for BOTH tensors in one launch. Fully lane-dense:
// thread loads float4 at base+tid*4 and base+1024+tid*4, stores bf16x4 (8B) each.
__global__ __launch_bounds__(256) void cvt2_kernel(const float* __restrict__ a, bf16_t* __restrict__ da,
                                                   int nblk_a,
                                                   const float* __restrict__ w, bf16_t* __restrict__ dw) {
    int b = blockIdx.x;
    const float* src;
    bf16_t* dst;
    if (b < nblk_a) { src = a; dst = da; }
    else            { src = w; dst = dw; b -= nblk_a; }
    const size_t base = (size_t)b * 2048 + threadIdx.x * 4;
    const float4 v0 = *(const float4*)(src + base);
    const float4 v1 = *(const float4*)(src + base + 1024);
    bf16x4 o0, o1;
    o0[0] = (bf16_t)v0.x; o0[1] = (bf16_t)v0.y; o0[2] = (bf16_t)v0.z; o0[3] = (bf16_t)v0.w;
    o1[0] = (bf16_t)v1.x; o1[1] = (bf16_t)v1.y; o1[2] = (bf16_t)v1.z; o1[3] = (bf16_t)v1.w;
    *(bf16x4*)(dst + base) = o0;
    *(bf16x4*)(dst + base + 1024) = o1;
}

// C[t,o] = sum_k A[t,k]*B[o,k] (NT gemm), fused dequant epilogue.
// 128x128 block tile, BK=32, 4 waves 2x2, each wave 64x64 via 4x4 16x16x32 MFMAs.
// LDS layout: row r's 8-elem k-chunk c stored at physical chunk c ^ ((r>>1)&3)
// -> ds_read_b128 start-banks within each 16-lane phase are 8-distinct (2-way only).
template <bool USE_DMA>
__global__ __launch_bounds__(256, 4) void gemm_kernel(
    const bf16_t* __restrict__ A, const bf16_t* __restrict__ B,
    const float* __restrict__ Afp, const float* __restrict__ Bfp,
    const float* __restrict__ scale_x, const float* __restrict__ scale_w,
    const float* __restrict__ gscale, const float* __restrict__ bias,
    float* __restrict__ out) {
    __shared__ bf16_t sA[BM * BK];  // 8 KiB
    __shared__ bf16_t sB[BN * BK];  // 8 KiB

    const int tid = threadIdx.x;
    const int bn = blockIdx.x & 31;   // 32 N-tiles
    const int bm = blockIdx.x >> 5;   // 64 M-tiles
    const int row0 = bm * BM;
    const int col0 = bn * BN;

    const int lane = tid & 63;
    const int wid = tid >> 6;
    const int wm = (wid >> 1) * 64;
    const int wn = (wid & 1) * 64;
    const int fr = lane & 15;         // row (A) / col (B) within 16
    const int q  = lane >> 4;         // k-quad: global chunk index 0..3 (k = q*8..q*8+7)
    const int s_fr = (fr >> 1) & 3;   // row-dependent chunk swizzle
    const int kc = ((q ^ s_fr) * 8);  // physical chunk offset for fragment reads

    f32x4 acc[4][4] = {};

    // DMA staging: thread t fills LDS slot (row t>>2, chunk t&3); the slot must
    // hold GLOBAL chunk (t&3) ^ s(row), s(row) = ((t>>2)>>1)&3 = (t>>3)&3.
    const int r_half = tid >> 2;                       // 0..63 (and +64 for 2nd half)
    const int c_g = (tid & 3) ^ ((tid >> 3) & 3);      // swizzled global chunk
    const size_t a_g = (size_t)(row0 + r_half) * KDIM + c_g * 8;
    const size_t b_g = (size_t)(col0 + r_half) * KDIM + c_g * 8;
    const int lds_off = tid * 8;  // elements (16 B/thread, lane-ordered)

    for (int k0 = 0; k0 < KDIM; k0 += BK) {
        if (USE_DMA) {
            async_ld16(&sA[lds_off],        A + a_g + k0);
            async_ld16(&sA[2048 + lds_off], A + a_g + (size_t)64 * KDIM + k0);
            async_ld16(&sB[lds_off],        B + b_g + k0);
            async_ld16(&sB[2048 + lds_off], B + b_g + (size_t)64 * KDIM + k0);
        } else {
            // fallback: fp32 load + cvt + swizzled ds_write (same physical layout)
            const int r = tid >> 2;
            const int cg2 = (tid & 3) ^ ((tid >> 3) & 3);
#pragma unroll
            for (int h = 0; h < 2; ++h) {
                const int rr = r + h * 64;
                const float4 va0 = *(const float4*)(Afp + (size_t)(row0 + rr) * KDIM + k0 + cg2 * 8);
                const float4 va1 = *(const float4*)(Afp + (size_t)(row0 + rr) * KDIM + k0 + cg2 * 8 + 4);
                const float4 vb0 = *(const float4*)(Bfp + (size_t)(col0 + rr) * KDIM + k0 + cg2 * 8);
                const float4 vb1 = *(const float4*)(Bfp + (size_t)(col0 + rr) * KDIM + k0 + cg2 * 8 + 4);
                bf16x8 pa, pb;
                pa[0] = (bf16_t)va0.x; pa[1] = (bf16_t)va0.y; pa[2] = (bf16_t)va0.z; pa[3] = (bf16_t)va0.w;
                pa[4] = (bf16_t)va1.x; pa[5] = (bf16_t)va1.y; pa[6] = (bf16_t)va1.z; pa[7] = (bf16_t)va1.w;
                pb[0] = (bf16_t)vb0.x; pb[1] = (bf16_t)vb0.y; pb[2] = (bf16_t)vb0.z; pb[3] = (bf16_t)vb0.w;
                pb[4] = (bf16_t)vb1.x; pb[5] = (bf16_t)vb1.y; pb[6] = (bf16_t)vb1.z; pb[7] = (bf16_t)vb1.w;
                *(bf16x8*)&sA[rr * BK + (tid & 3) * 8] = pa;
                *(bf16x8*)&sB[rr * BK + (tid & 3) * 8] = pb;
            }
        }
        __syncthreads();

        bf16x8 af[4], bfr[4];
#pragma unroll
        for (int mt = 0; mt < 4; ++mt)
            af[mt] = *(const bf16x8*)&sA[(wm + mt * 16 + fr) * BK + kc];
#pragma unroll
        for (int nt = 0; nt < 4; ++nt)
            bfr[nt] = *(const bf16x8*)&sB[(wn + nt * 16 + fr) * BK + kc];
#pragma unroll
        for (int mt = 0; mt < 4; ++mt)
#pragma unroll
            for (int nt = 0; nt < 4; ++nt)
                acc[mt][nt] = __builtin_amdgcn_mfma_f32_16x16x32_bf16(af[mt], bfr[nt], acc[mt][nt], 0, 0, 0);
        __syncthreads();
    }

    // Epilogue: C/D layout col=lane&15, row=(lane>>4)*4+reg [m89/m91-verified]
    const float gs = gscale[0];
    const int rbase = q * 4;
#pragma unroll
    for (int nt = 0; nt < 4; ++nt) {
        const int o = col0 + wn + nt * 16 + fr;
        const float swv = scale_w[o] * gs;
        const float bv = bias[o];
#pragma unroll
        for (int mt = 0; mt < 4; ++mt) {
#pragma unroll
            for (int i = 0; i < 4; ++i) {
                const int t = row0 + wm + mt * 16 + rbase + i;
                out[(size_t)t * ODIM + o] = acc[mt][nt][i] * (scale_x[t] * swv) + bv;
            }
        }
    }
}

extern "C" void kernel_launch(void* const* d_in, const int* in_sizes, int n_in,
                              void* d_out, int out_size, void* d_ws, size_t ws_size,
                              hipStream_t stream) {
    const float* qx   = (const float*)d_in[0];  // (T,K)
    const float* W    = (const float*)d_in[1];  // (O,K)
    const float* sx   = (const float*)d_in[2];  // (T,1)
    const float* sw   = (const float*)d_in[3];  // (O,)
    const float* gs   = (const float*)d_in[4];  // (1,)
    const float* bias = (const float*)d_in[5];  // (O,)
    float* out = (float*)d_out;

    const size_t nA = (size_t)TDIM * KDIM;
    const size_t nW = (size_t)ODIM * KDIM;
    const dim3 grid(2048);  // 64 M-tiles x 32 N-tiles

    if (ws_size >= (nA + nW) * sizeof(bf16_t)) {
        bf16_t* Abf = (bf16_t*)d_ws;
        bf16_t* Wbf = Abf + nA;
        const int nblk_a = (int)(nA / 2048);
        const int nblk_w = (int)(nW / 2048);
        cvt2_kernel<<<dim3(nblk_a + nblk_w), dim3(256), 0, stream>>>(qx, Abf, nblk_a, W, Wbf);
        gemm_kernel<true><<<grid, dim3(256), 0, stream>>>(
            Abf, Wbf, nullptr, nullptr, sx, sw, gs, bias, out);
    } else {
        gemm_kernel<false><<<grid, dim3(256), 0, stream>>>(
            nullptr, nullptr, qx, W, sx, sw, gs, bias, out);
    }
}